// Round 1
// baseline (161.209 us; speedup 1.0000x reference)
//
#include <hip/hip_runtime.h>

typedef unsigned int uint;
typedef unsigned short ushort;
typedef __attribute__((ext_vector_type(8))) short short8;
typedef __attribute__((ext_vector_type(4))) float f32x4;

#define B_   512
#define V_   256
#define M_   128
#define H_   512
#define T_   16
#define KTOT 34816   // V_*M_ + M_*T_

// ---------------- helpers ----------------
__device__ __forceinline__ ushort f2bf(float f) {
  uint u = __builtin_bit_cast(uint, f);
  u += 0x7fffu + ((u >> 16) & 1u);   // RNE
  return (ushort)(u >> 16);
}

// ---------------- kernel 1: per-batch prep ----------------
// - idx = argmin(memory_surprise[b]) (first min)
// - t = timings+1, t[idx]=0
// - stable rank -> order (slot->row), sorted_t
// - write bits region of A (bf16 0/1), gather memory rows (x replaces row idx) -> A bf16
// - h_pre[b][:] = b1
__global__ __launch_bounds__(256) void prep_kernel(
    const float* __restrict__ x, const float* __restrict__ mem,
    const int* __restrict__ timings, const float* __restrict__ msurp,
    const float* __restrict__ b1,
    ushort* __restrict__ A, float* __restrict__ h_pre)
{
  const int b = blockIdx.x, tid = threadIdx.x;
  __shared__ int s_t[M_];
  __shared__ int s_row[M_];
  __shared__ int s_st[M_];
  __shared__ int s_idx;

  if (tid < 64) {
    float v0 = msurp[b * M_ + tid];
    float v1 = msurp[b * M_ + tid + 64];
    float v; int i;
    if (v1 < v0) { v = v1; i = tid + 64; } else { v = v0; i = tid; }
    #pragma unroll
    for (int off = 32; off > 0; off >>= 1) {
      float ov = __shfl_down(v, off);
      int   oi = __shfl_down(i, off);
      if (ov < v || (ov == v && oi < i)) { v = ov; i = oi; }
    }
    if (tid == 0) s_idx = i;
  }
  __syncthreads();
  const int idx = s_idx;

  if (tid < M_) {
    int t = timings[b * M_ + tid] + 1;
    if (tid == idx) t = 0;
    s_t[tid] = t;
  }
  // h_pre init (independent of s_t)
  h_pre[(size_t)b * H_ + tid]       = b1[tid];
  h_pre[(size_t)b * H_ + 256 + tid] = b1[256 + tid];
  __syncthreads();

  if (tid < M_) {
    const int t = s_t[tid];
    int r = 0;
    for (int j = 0; j < M_; ++j) {
      int tj = s_t[j];
      r += (tj < t || (tj == t && j < tid)) ? 1 : 0;
    }
    s_row[r] = tid;   // order[r] = tid
    s_st[r]  = t;     // sorted_t[r]
  }
  __syncthreads();

  // bits: pred_in[32768 + slot*16 + k] = (sorted_t[slot] >> k) & 1
  if (tid < M_) {
    const int t = s_st[tid];
    uint p[8];
    #pragma unroll
    for (int h = 0; h < 8; ++h) {
      uint lo = ((t >> (2 * h)) & 1) ? 0x3F80u : 0u;
      uint hi = ((t >> (2 * h + 1)) & 1) ? 0x3F80u : 0u;
      p[h] = lo | (hi << 16);
    }
    uint4* dst = (uint4*)(A + (size_t)b * KTOT + V_ * M_ + tid * T_);
    uint4 w0; w0.x = p[0]; w0.y = p[1]; w0.z = p[2]; w0.w = p[3];
    uint4 w1; w1.x = p[4]; w1.y = p[5]; w1.z = p[6]; w1.w = p[7];
    dst[0] = w0; dst[1] = w1;
  }

  // gather: A[b][slot*256 + v] = bf16( (order[slot]==idx ? x[b] : memory[b][order[slot]])[v] )
  const int lane = tid & 63, sub = tid >> 6;
  for (int it = 0; it < 32; ++it) {
    const int slot = it * 4 + sub;
    const int rowm = s_row[slot];
    const float* src = (rowm == idx) ? (x + (size_t)b * V_)
                                     : (mem + ((size_t)b * M_ + rowm) * V_);
    f32x4 v = *(const f32x4*)(src + lane * 4);
    uint2 o;
    o.x = (uint)f2bf(v[0]) | ((uint)f2bf(v[1]) << 16);
    o.y = (uint)f2bf(v[2]) | ((uint)f2bf(v[3]) << 16);
    *(uint2*)(A + (size_t)b * KTOT + slot * V_ + lane * 4) = o;
  }
}

// ---------------- kernel 2: W1 [K][512] f32 -> W1T [512][K] bf16 ----------------
__global__ __launch_bounds__(256) void transpose_w1_kernel(
    const float* __restrict__ W1, ushort* __restrict__ W1T)
{
  const int kt = blockIdx.x;            // KTOT/512 = 68
  const int nt = blockIdx.y;            // H_/64 = 8
  const int wave = threadIdx.x >> 6, lane = threadIdx.x & 63;
  const int n = nt * 64 + lane;
  const int kbase = kt * 512 + wave * 128;
  for (int c = 0; c < 16; ++c) {
    const int k = kbase + c * 8;
    const float* src = W1 + (size_t)k * H_ + n;   // column n, 8 consecutive k
    float v0 = src[0 * H_], v1 = src[1 * H_], v2 = src[2 * H_], v3 = src[3 * H_];
    float v4 = src[4 * H_], v5 = src[5 * H_], v6 = src[6 * H_], v7 = src[7 * H_];
    uint4 o;
    o.x = (uint)f2bf(v0) | ((uint)f2bf(v1) << 16);
    o.y = (uint)f2bf(v2) | ((uint)f2bf(v3) << 16);
    o.z = (uint)f2bf(v4) | ((uint)f2bf(v5) << 16);
    o.w = (uint)f2bf(v6) | ((uint)f2bf(v7) << 16);
    *(uint4*)(W1T + (size_t)n * KTOT + k) = o;
  }
}

// ---------------- kernel 3: split-K bf16 MFMA GEMM ----------------
// h_pre[b][n] += sum_k A[b][k] * W1T[n][k];  BM=256 BN=128 SPLITK=32 -> 256 blocks
#define BM 256
#define BN 128
#define SPLITK 32
#define KCH (KTOT / SPLITK)   // 1088
#define NCHU (KCH / 32)       // 34

#define GLD16(g, l) __builtin_amdgcn_global_load_lds( \
  (const __attribute__((address_space(1))) void*)(g), \
  (__attribute__((address_space(3))) void*)(l), 16, 0, 0)

__global__ __launch_bounds__(512) void gemm1_kernel(
    const ushort* __restrict__ A, const ushort* __restrict__ Bt,
    float* __restrict__ h_pre)
{
  __shared__ __align__(16) ushort As[2][BM * 32];
  __shared__ __align__(16) ushort Bs[2][BN * 32];

  const int bid  = blockIdx.x;
  const int tile = bid & 7;      // 2 m-tiles x 4 n-tiles
  const int sk   = bid >> 3;     // 0..31
  const int b0   = (tile >> 2) * BM;
  const int n0   = (tile & 3) * BN;
  const int tid  = threadIdx.x, wave = tid >> 6, lane = tid & 63;
  const int wm   = wave >> 1;    // 0..3 (64 rows each)
  const int wn   = wave & 1;     // 0..1 (64 cols each)
  const long kb0 = (long)sk * KCH;

  f32x4 acc[4][4];
  #pragma unroll
  for (int i = 0; i < 4; ++i)
    #pragma unroll
    for (int j = 0; j < 4; ++j) acc[i][j] = (f32x4)0.f;

  const int ar  = wave * 32 + (lane >> 2);   // staged A row (16 rows/pass, 2 passes)
  const int bn  = wave * 16 + (lane >> 2);   // staged B row (col n)
  const int akk = (lane & 3) * 8;            // k offset within 32-chunk

  auto stage = [&](int buf, long kb) {
    // LDS dest = wave-uniform base + lane*16B -> row-major [rows][32] bf16
    GLD16(A  + ((size_t)(b0 + ar))      * KTOT + kb + akk, &As[buf][(wave * 32) * 32]);
    GLD16(A  + ((size_t)(b0 + ar + 16)) * KTOT + kb + akk, &As[buf][(wave * 32 + 16) * 32]);
    GLD16(Bt + ((size_t)(n0 + bn))      * KTOT + kb + akk, &Bs[buf][(wave * 16) * 32]);
  };

  stage(0, kb0);
  int cur = 0;
  for (int c = 0; c < NCHU; ++c) {
    __syncthreads();                           // drains stage loads (vmcnt before barrier)
    if (c + 1 < NCHU) stage(cur ^ 1, kb0 + (long)(c + 1) * 32);
    const ushort* as = &As[cur][(wm * 64 + (lane & 15)) * 32 + (lane >> 4) * 8];
    const ushort* bs = &Bs[cur][(wn * 64 + (lane & 15)) * 32 + (lane >> 4) * 8];
    short8 af[4], bf[4];
    #pragma unroll
    for (int i = 0; i < 4; ++i) {
      af[i] = *(const short8*)(as + i * 16 * 32);
      bf[i] = *(const short8*)(bs + i * 16 * 32);
    }
    #pragma unroll
    for (int i = 0; i < 4; ++i)
      #pragma unroll
      for (int j = 0; j < 4; ++j)
        acc[i][j] = __builtin_amdgcn_mfma_f32_16x16x32_bf16(af[i], bf[j], acc[i][j], 0, 0, 0);
    cur ^= 1;
  }

  // epilogue: atomic split-K reduction (device-scope by default)
  const int row0 = b0 + wm * 64 + (lane >> 4) * 4;
  const int col0 = n0 + wn * 64 + (lane & 15);
  #pragma unroll
  for (int i = 0; i < 4; ++i)
    #pragma unroll
    for (int j = 0; j < 4; ++j)
      #pragma unroll
      for (int r = 0; r < 4; ++r)
        atomicAdd(&h_pre[(size_t)(row0 + i * 16 + r) * H_ + col0 + j * 16], acc[i][j][r]);
}

// ---------------- kernel 4: out = relu(h_pre) @ W2 + b2 (fp32) ----------------
__global__ __launch_bounds__(256) void gemm2_kernel(
    const float* __restrict__ h_pre, const float* __restrict__ W2,
    const float* __restrict__ b2, float* __restrict__ out)
{
  const int bb = blockIdx.x * 4;   // 128 blocks, 4 batch rows each
  const int v  = threadIdx.x;      // 0..255 output col
  __shared__ float hs[4][H_];
  #pragma unroll
  for (int i = 0; i < 8; ++i) {
    int id = i * 256 + v;
    hs[id >> 9][id & 511] =
        fmaxf(h_pre[(size_t)(bb + (id >> 9)) * H_ + (id & 511)], 0.f);
  }
  __syncthreads();
  float a0 = 0.f, a1 = 0.f, a2 = 0.f, a3 = 0.f;
  for (int j4 = 0; j4 < H_ / 4; ++j4) {
    f32x4 h0 = *(const f32x4*)&hs[0][j4 * 4];
    f32x4 h1 = *(const f32x4*)&hs[1][j4 * 4];
    f32x4 h2 = *(const f32x4*)&hs[2][j4 * 4];
    f32x4 h3 = *(const f32x4*)&hs[3][j4 * 4];
    #pragma unroll
    for (int t = 0; t < 4; ++t) {
      float w = W2[(size_t)(j4 * 4 + t) * V_ + v];   // coalesced across lanes
      a0 += h0[t] * w; a1 += h1[t] * w; a2 += h2[t] * w; a3 += h3[t] * w;
    }
  }
  const float bias = b2[v];
  out[(size_t)(bb + 0) * V_ + v] = a0 + bias;
  out[(size_t)(bb + 1) * V_ + v] = a1 + bias;
  out[(size_t)(bb + 2) * V_ + v] = a2 + bias;
  out[(size_t)(bb + 3) * V_ + v] = a3 + bias;
}

// ---------------- launch ----------------
extern "C" void kernel_launch(void* const* d_in, const int* in_sizes, int n_in,
                              void* d_out, int out_size, void* d_ws, size_t ws_size,
                              hipStream_t stream) {
  const float* x   = (const float*)d_in[0];
  const float* mem = (const float*)d_in[1];
  const int*   tim = (const int*)d_in[2];
  const float* msu = (const float*)d_in[3];
  // d_in[4] = last_prediction : dead w.r.t. output
  const float* W1  = (const float*)d_in[5];
  const float* b1  = (const float*)d_in[6];
  const float* W2  = (const float*)d_in[7];
  const float* b2  = (const float*)d_in[8];
  float* out = (float*)d_out;

  char* ws = (char*)d_ws;
  const size_t abytes = (size_t)B_ * KTOT * 2;       // 35,651,584 B each
  ushort* A_ws  = (ushort*)ws;                       // [512][34816] bf16
  ushort* W1T   = (ushort*)(ws + abytes);            // [512][34816] bf16
  float*  h_pre = (float*)(ws + 2 * abytes);         // [512][512] f32 (needs ~72 MB ws total)

  prep_kernel<<<B_, 256, 0, stream>>>(x, mem, tim, msu, b1, A_ws, h_pre);
  transpose_w1_kernel<<<dim3(KTOT / 512, H_ / 64), 256, 0, stream>>>(W1, W1T);
  gemm1_kernel<<<256, 512, 0, stream>>>(A_ws, W1T, h_pre);
  gemm2_kernel<<<B_ / 4, 256, 0, stream>>>(h_pre, W2, b2, out);
}

// Round 2
// 121.230 us; speedup vs baseline: 1.3298x; 1.3298x over previous
//
#include <hip/hip_runtime.h>

typedef unsigned int uint;
typedef unsigned short ushort;
typedef __attribute__((ext_vector_type(8))) short short8;
typedef __attribute__((ext_vector_type(4))) float f32x4;

#define B_   512
#define V_   256
#define M_   128
#define H_   512
#define T_   16
#define KTOT 34816   // V_*M_ + M_*T_

// ---------------- helpers ----------------
__device__ __forceinline__ ushort f2bf(float f) {
  uint u = __builtin_bit_cast(uint, f);
  u += 0x7fffu + ((u >> 16) & 1u);   // RNE
  return (ushort)(u >> 16);
}

// ---------------- kernel 1: per-batch prep ----------------
__global__ __launch_bounds__(256) void prep_kernel(
    const float* __restrict__ x, const float* __restrict__ mem,
    const int* __restrict__ timings, const float* __restrict__ msurp,
    const float* __restrict__ b1,
    ushort* __restrict__ A, float* __restrict__ h_pre)
{
  const int b = blockIdx.x, tid = threadIdx.x;
  __shared__ int s_t[M_];
  __shared__ int s_row[M_];
  __shared__ int s_st[M_];
  __shared__ int s_idx;

  if (tid < 64) {
    float v0 = msurp[b * M_ + tid];
    float v1 = msurp[b * M_ + tid + 64];
    float v; int i;
    if (v1 < v0) { v = v1; i = tid + 64; } else { v = v0; i = tid; }
    #pragma unroll
    for (int off = 32; off > 0; off >>= 1) {
      float ov = __shfl_down(v, off);
      int   oi = __shfl_down(i, off);
      if (ov < v || (ov == v && oi < i)) { v = ov; i = oi; }
    }
    if (tid == 0) s_idx = i;
  }
  __syncthreads();
  const int idx = s_idx;

  if (tid < M_) {
    int t = timings[b * M_ + tid] + 1;
    if (tid == idx) t = 0;
    s_t[tid] = t;
  }
  h_pre[(size_t)b * H_ + tid]       = b1[tid];
  h_pre[(size_t)b * H_ + 256 + tid] = b1[256 + tid];
  __syncthreads();

  if (tid < M_) {
    const int t = s_t[tid];
    int r = 0;
    for (int j = 0; j < M_; ++j) {
      int tj = s_t[j];
      r += (tj < t || (tj == t && j < tid)) ? 1 : 0;
    }
    s_row[r] = tid;   // order[r] = tid
    s_st[r]  = t;     // sorted_t[r]
  }
  __syncthreads();

  // bits region
  if (tid < M_) {
    const int t = s_st[tid];
    uint p[8];
    #pragma unroll
    for (int h = 0; h < 8; ++h) {
      uint lo = ((t >> (2 * h)) & 1) ? 0x3F80u : 0u;
      uint hi = ((t >> (2 * h + 1)) & 1) ? 0x3F80u : 0u;
      p[h] = lo | (hi << 16);
    }
    uint4* dst = (uint4*)(A + (size_t)b * KTOT + V_ * M_ + tid * T_);
    uint4 w0; w0.x = p[0]; w0.y = p[1]; w0.z = p[2]; w0.w = p[3];
    uint4 w1; w1.x = p[4]; w1.y = p[5]; w1.z = p[6]; w1.w = p[7];
    dst[0] = w0; dst[1] = w1;
  }

  // gather rows
  const int lane = tid & 63, sub = tid >> 6;
  for (int it = 0; it < 32; ++it) {
    const int slot = it * 4 + sub;
    const int rowm = s_row[slot];
    const float* src = (rowm == idx) ? (x + (size_t)b * V_)
                                     : (mem + ((size_t)b * M_ + rowm) * V_);
    f32x4 v = *(const f32x4*)(src + lane * 4);
    uint2 o;
    o.x = (uint)f2bf(v[0]) | ((uint)f2bf(v[1]) << 16);
    o.y = (uint)f2bf(v[2]) | ((uint)f2bf(v[3]) << 16);
    *(uint2*)(A + (size_t)b * KTOT + slot * V_ + lane * 4) = o;
  }
}

// ---------------- kernel 2: LDS-tiled transpose  W1[K][512] f32 -> W1T[512][K] bf16
// 64x64 tiles. Coalesced float4 reads -> LDS -> contiguous bf16 writes along k.
__global__ __launch_bounds__(256) void transpose_w1_kernel(
    const float* __restrict__ W1, ushort* __restrict__ W1T)
{
  __shared__ float tile[64][68];     // 68-pad: rows 272B (16B-aligned)
  const int kt = blockIdx.x * 64;
  const int nt = blockIdx.y * 64;
  const int tid = threadIdx.x;

  // read: thread -> 4 rows, float4 along n. Lanes 0..15 cover one 256B row seg.
  {
    const int rn4 = (tid & 15) * 4;
    const int rk  = tid >> 4;        // 0..15
    #pragma unroll
    for (int p = 0; p < 4; ++p) {
      const int k = rk + p * 16;
      f32x4 v = *(const f32x4*)(W1 + (size_t)(kt + k) * H_ + nt + rn4);
      *(f32x4*)&tile[k][rn4] = v;
    }
  }
  __syncthreads();

  // write: thread -> row n = tid>>2, k-chunk (tid&3)*16; 16 bf16 = 2x uint4
  {
    const int wn = tid >> 2;
    const int wk = (tid & 3) * 16;
    uint w[8];
    #pragma unroll
    for (int c = 0; c < 8; ++c) {
      float lo = tile[wk + 2 * c][wn];
      float hi = tile[wk + 2 * c + 1][wn];
      w[c] = (uint)f2bf(lo) | ((uint)f2bf(hi) << 16);
    }
    uint4* dst = (uint4*)(W1T + (size_t)(nt + wn) * KTOT + kt + wk);
    uint4 o0; o0.x = w[0]; o0.y = w[1]; o0.z = w[2]; o0.w = w[3];
    uint4 o1; o1.x = w[4]; o1.y = w[5]; o1.z = w[6]; o1.w = w[7];
    dst[0] = o0; dst[1] = o1;
  }
}

// ---------------- kernel 3: split-K bf16 MFMA GEMM ----------------
#define BM 256
#define BN 128
#define SPLITK 32
#define KCH (KTOT / SPLITK)   // 1088
#define NCHU (KCH / 32)       // 34

#define GLD16(g, l) __builtin_amdgcn_global_load_lds( \
  (const __attribute__((address_space(1))) void*)(g), \
  (__attribute__((address_space(3))) void*)(l), 16, 0, 0)

__global__ __launch_bounds__(512) void gemm1_kernel(
    const ushort* __restrict__ A, const ushort* __restrict__ Bt,
    float* __restrict__ h_pre)
{
  __shared__ __align__(16) ushort As[2][BM * 32];
  __shared__ __align__(16) ushort Bs[2][BN * 32];

  const int bid  = blockIdx.x;
  const int tile = bid & 7;      // 2 m-tiles x 4 n-tiles
  const int sk   = bid >> 3;     // 0..31
  const int b0   = (tile >> 2) * BM;
  const int n0   = (tile & 3) * BN;
  const int tid  = threadIdx.x, wave = tid >> 6, lane = tid & 63;
  const int wm   = wave >> 1;
  const int wn   = wave & 1;
  const long kb0 = (long)sk * KCH;

  f32x4 acc[4][4];
  #pragma unroll
  for (int i = 0; i < 4; ++i)
    #pragma unroll
    for (int j = 0; j < 4; ++j) acc[i][j] = (f32x4)0.f;

  const int ar  = wave * 32 + (lane >> 2);
  const int bn  = wave * 16 + (lane >> 2);
  const int akk = (lane & 3) * 8;

  auto stage = [&](int buf, long kb) {
    GLD16(A  + ((size_t)(b0 + ar))      * KTOT + kb + akk, &As[buf][(wave * 32) * 32]);
    GLD16(A  + ((size_t)(b0 + ar + 16)) * KTOT + kb + akk, &As[buf][(wave * 32 + 16) * 32]);
    GLD16(Bt + ((size_t)(n0 + bn))      * KTOT + kb + akk, &Bs[buf][(wave * 16) * 32]);
  };

  stage(0, kb0);
  int cur = 0;
  for (int c = 0; c < NCHU; ++c) {
    __syncthreads();
    if (c + 1 < NCHU) stage(cur ^ 1, kb0 + (long)(c + 1) * 32);
    const ushort* as = &As[cur][(wm * 64 + (lane & 15)) * 32 + (lane >> 4) * 8];
    const ushort* bs = &Bs[cur][(wn * 64 + (lane & 15)) * 32 + (lane >> 4) * 8];
    short8 af[4], bf[4];
    #pragma unroll
    for (int i = 0; i < 4; ++i) {
      af[i] = *(const short8*)(as + i * 16 * 32);
      bf[i] = *(const short8*)(bs + i * 16 * 32);
    }
    #pragma unroll
    for (int i = 0; i < 4; ++i)
      #pragma unroll
      for (int j = 0; j < 4; ++j)
        acc[i][j] = __builtin_amdgcn_mfma_f32_16x16x32_bf16(af[i], bf[j], acc[i][j], 0, 0, 0);
    cur ^= 1;
  }

  const int row0 = b0 + wm * 64 + (lane >> 4) * 4;
  const int col0 = n0 + wn * 64 + (lane & 15);
  #pragma unroll
  for (int i = 0; i < 4; ++i)
    #pragma unroll
    for (int j = 0; j < 4; ++j)
      #pragma unroll
      for (int r = 0; r < 4; ++r)
        atomicAdd(&h_pre[(size_t)(row0 + i * 16 + r) * H_ + col0 + j * 16], acc[i][j][r]);
}

// ---------------- kernel 4: out = relu(h_pre) @ W2 + b2 (fp32) ----------------
__global__ __launch_bounds__(256) void gemm2_kernel(
    const float* __restrict__ h_pre, const float* __restrict__ W2,
    const float* __restrict__ b2, float* __restrict__ out)
{
  const int bb = blockIdx.x * 4;
  const int v  = threadIdx.x;
  __shared__ float hs[4][H_];
  #pragma unroll
  for (int i = 0; i < 8; ++i) {
    int id = i * 256 + v;
    hs[id >> 9][id & 511] =
        fmaxf(h_pre[(size_t)(bb + (id >> 9)) * H_ + (id & 511)], 0.f);
  }
  __syncthreads();
  float a0 = 0.f, a1 = 0.f, a2 = 0.f, a3 = 0.f;
  for (int j4 = 0; j4 < H_ / 4; ++j4) {
    f32x4 h0 = *(const f32x4*)&hs[0][j4 * 4];
    f32x4 h1 = *(const f32x4*)&hs[1][j4 * 4];
    f32x4 h2 = *(const f32x4*)&hs[2][j4 * 4];
    f32x4 h3 = *(const f32x4*)&hs[3][j4 * 4];
    #pragma unroll
    for (int t = 0; t < 4; ++t) {
      float w = W2[(size_t)(j4 * 4 + t) * V_ + v];
      a0 += h0[t] * w; a1 += h1[t] * w; a2 += h2[t] * w; a3 += h3[t] * w;
    }
  }
  const float bias = b2[v];
  out[(size_t)(bb + 0) * V_ + v] = a0 + bias;
  out[(size_t)(bb + 1) * V_ + v] = a1 + bias;
  out[(size_t)(bb + 2) * V_ + v] = a2 + bias;
  out[(size_t)(bb + 3) * V_ + v] = a3 + bias;
}

// ---------------- launch ----------------
extern "C" void kernel_launch(void* const* d_in, const int* in_sizes, int n_in,
                              void* d_out, int out_size, void* d_ws, size_t ws_size,
                              hipStream_t stream) {
  const float* x   = (const float*)d_in[0];
  const float* mem = (const float*)d_in[1];
  const int*   tim = (const int*)d_in[2];
  const float* msu = (const float*)d_in[3];
  const float* W1  = (const float*)d_in[5];
  const float* b1  = (const float*)d_in[6];
  const float* W2  = (const float*)d_in[7];
  const float* b2  = (const float*)d_in[8];
  float* out = (float*)d_out;

  char* ws = (char*)d_ws;
  const size_t abytes = (size_t)B_ * KTOT * 2;
  ushort* A_ws  = (ushort*)ws;
  ushort* W1T   = (ushort*)(ws + abytes);
  float*  h_pre = (float*)(ws + 2 * abytes);

  prep_kernel<<<B_, 256, 0, stream>>>(x, mem, tim, msu, b1, A_ws, h_pre);
  transpose_w1_kernel<<<dim3(KTOT / 64, H_ / 64), 256, 0, stream>>>(W1, W1T);
  gemm1_kernel<<<256, 512, 0, stream>>>(A_ws, W1T, h_pre);
  gemm2_kernel<<<B_ / 4, 256, 0, stream>>>(h_pre, W2, b2, out);
}